// Round 7
// baseline (354.788 us; speedup 1.0000x reference)
//
#include <hip/hip_runtime.h>
#include <stdint.h>
#include <math.h>

// ---------------------------------------------------------------------------
// GAT + PairNorm + ReLU, MI355X (gfx950).  Round 7.
// R6 post-mortem: k_gemm top at 45.9us, MfmaUtil 12%, 1.93M LDS bank
// conflicts (BK=32 row stride 64B -> 8-way on ds_read_b128), 16 barrier
// pairs for 16 MFMA each. Changes:
//  * GEMM: BK=64 (8 K-iters, 32 MFMA/barrier) + LDS row pad +8 u16
//    (stride 144B -> 2-way conflicts = free per m136).
//  * k_rowdots DELETED: a_s/a_d computed in GEMM epilogue from fp32 acc
//    (shuffle-reduce over l16, depth-4 atomicAdd per row). Saves 30.8MB
//    h re-read + a launch.
// RNG: JAX partitionable threefry (fold-like split; bits = o0^o1).
// ---------------------------------------------------------------------------

#define N_NODES 30000
#define MPAD    30080
#define DIM     512
#define NEDGE   300000
#define ETOT    330000
#define AGG_BLOCKS 7500
#define RED_BLOCKS 60
#define RED_ROWS   125
#define LDSW    72               // 64 + 8 pad, u16 units

typedef unsigned int u32;
typedef unsigned short u16;

typedef __attribute__((ext_vector_type(8))) short bf16x8;
typedef __attribute__((ext_vector_type(4))) float f32x4;

// ----------------------------- threefry2x32 --------------------------------
__host__ __device__ __forceinline__ void threefry2x32(u32 k0, u32 k1, u32 x0, u32 x1,
                                                      u32& o0, u32& o1) {
  u32 ks2 = k0 ^ k1 ^ 0x1BD11BDAu;
#define TF_R(r) { x0 += x1; x1 = (x1 << r) | (x1 >> (32 - r)); x1 ^= x0; }
  x0 += k0; x1 += k1;
  TF_R(13) TF_R(15) TF_R(26) TF_R(6)
  x0 += k1; x1 += ks2 + 1u;
  TF_R(17) TF_R(29) TF_R(16) TF_R(24)
  x0 += ks2; x1 += k0 + 2u;
  TF_R(13) TF_R(15) TF_R(26) TF_R(6)
  x0 += k0; x1 += k1 + 3u;
  TF_R(17) TF_R(29) TF_R(16) TF_R(24)
  x0 += k1; x1 += ks2 + 4u;
  TF_R(13) TF_R(15) TF_R(26) TF_R(6)
  x0 += ks2; x1 += k0 + 5u;
#undef TF_R
  o0 = x0; o1 = x1;
}

__device__ __forceinline__ u32 tf_fold(u32 k0, u32 k1, u32 idx) {
  u32 a, b;
  threefry2x32(k0, k1, 0u, idx, a, b);
  return a ^ b;
}

__device__ __forceinline__ float bf2f(u32 bits16) {
  return __uint_as_float(bits16 << 16);
}
__device__ __forceinline__ u16 f2bf(float f) {   // RNE
  u32 u = __float_as_uint(f);
  return (u16)((u + 0x7fffu + ((u >> 16) & 1u)) >> 16);
}

// ------------------- K0: W (fp32) -> Wt (bf16, transposed) -----------------
__global__ __launch_bounds__(256) void k_cvtW(const float* __restrict__ W,
                                              u16* __restrict__ Wt) {
  __shared__ u16 tile[32][33];
  int b = blockIdx.x;
  int bk = (b & 15) * 32, bn = (b >> 4) * 32;
  int c = threadIdx.x & 31, r = threadIdx.x >> 5;
#pragma unroll
  for (int rr = 0; rr < 32; rr += 8)
    tile[r + rr][c] = f2bf(W[(size_t)(bk + r + rr) * DIM + bn + c]);
  __syncthreads();
#pragma unroll
  for (int rr = 0; rr < 32; rr += 8)
    Wt[(size_t)(bn + r + rr) * DIM + bk + c] = tile[c][r + rr];
}

// ------------- K1: feature dropout (p=0.5) fp32 -> bf16, pad ---------------
__global__ __launch_bounds__(256) void k_dropout(const float* __restrict__ x,
                                                 u16* __restrict__ xd,
                                                 u32 kf0, u32 kf1) {
  size_t gid = (size_t)blockIdx.x * 256 + threadIdx.x;
  size_t i0 = gid * 8;
  if (i0 >= (size_t)MPAD * DIM) return;
  uint4 o = make_uint4(0u, 0u, 0u, 0u);
  if (i0 < (size_t)N_NODES * DIM) {
    float4 v0 = *(const float4*)(x + i0);
    float4 v1 = *(const float4*)(x + i0 + 4);
    float xv[8] = {v0.x, v0.y, v0.z, v0.w, v1.x, v1.y, v1.z, v1.w};
    u32 res[4];
#pragma unroll
    for (int p = 0; p < 4; p++) {
      u32 b0 = tf_fold(kf0, kf1, (u32)i0 + 2 * p);
      u32 b1 = tf_fold(kf0, kf1, (u32)i0 + 2 * p + 1);
      u32 r0 = (b0 >> 31) ? 0u : (u32)f2bf(2.0f * xv[2 * p]);     // keep <=> u<0.5
      u32 r1 = (b1 >> 31) ? 0u : (u32)f2bf(2.0f * xv[2 * p + 1]);
      res[p] = r0 | (r1 << 16);
    }
    o = make_uint4(res[0], res[1], res[2], res[3]);
  }
  *(uint4*)(xd + i0) = o;
}

// --------------------- K2: GEMM + fused attention dots ---------------------
// h[m][n] = sum_k xd[m][k]*Wt[n][k]. 128x128 tile, 4 waves, BK=64, padded
// LDS. Epilogue: H (bf16) + partial dots h.att_src / h.att_dst -> atomicAdd.
__global__ __launch_bounds__(256) void k_gemm(const u16* __restrict__ A,
                                              const u16* __restrict__ B,
                                              u16* __restrict__ H,
                                              const float* __restrict__ atts,
                                              const float* __restrict__ attd,
                                              float* __restrict__ a_s,
                                              float* __restrict__ a_d) {
  __shared__ __align__(16) u16 lA[128 * LDSW];
  __shared__ __align__(16) u16 lB[128 * LDSW];
  const int bn = (blockIdx.x & 3) * 128;
  const int bm = (blockIdx.x >> 2) * 128;
  const int tid = threadIdx.x;
  const int wave = tid >> 6, lane = tid & 63;
  const int quad = lane >> 4, l16 = lane & 15;
  const int wrow = (wave & 1) * 64, wcol = (wave >> 1) * 64;

  f32x4 acc[4][4] = {};

  for (int k0 = 0; k0 < DIM; k0 += 64) {
    uint4 ra[4], rb[4];
#pragma unroll
    for (int p = 0; p < 4; p++) {
      int idx = tid + p * 256;           // 0..1023
      int row = idx >> 3, c8 = idx & 7;  // 128 rows x 8 16B-chunks
      ra[p] = *(const uint4*)(A + (size_t)(bm + row) * DIM + k0 + c8 * 8);
      rb[p] = *(const uint4*)(B + (size_t)(bn + row) * DIM + k0 + c8 * 8);
    }
    __syncthreads();   // previous iteration's LDS reads must finish
#pragma unroll
    for (int p = 0; p < 4; p++) {
      int idx = tid + p * 256;
      int row = idx >> 3, c8 = idx & 7;
      *(uint4*)(lA + row * LDSW + c8 * 8) = ra[p];
      *(uint4*)(lB + row * LDSW + c8 * 8) = rb[p];
    }
    __syncthreads();

#pragma unroll
    for (int ks = 0; ks < 2; ks++) {
      bf16x8 af[4], bfr[4];
#pragma unroll
      for (int i = 0; i < 4; i++)
        af[i] = *(const bf16x8*)(lA + (wrow + i * 16 + l16) * LDSW + ks * 32 + quad * 8);
#pragma unroll
      for (int j = 0; j < 4; j++)
        bfr[j] = *(const bf16x8*)(lB + (wcol + j * 16 + l16) * LDSW + ks * 32 + quad * 8);
#pragma unroll
      for (int i = 0; i < 4; i++)
#pragma unroll
        for (int j = 0; j < 4; j++)
          acc[i][j] = __builtin_amdgcn_mfma_f32_16x16x32_bf16(af[i], bfr[j], acc[i][j], 0, 0, 0);
    }
  }

  // ---- epilogue: H write (C/D: col=lane&15, row=quad*4+reg) ----
#pragma unroll
  for (int i = 0; i < 4; i++) {
#pragma unroll
    for (int r = 0; r < 4; r++) {
      int row = bm + wrow + i * 16 + quad * 4 + r;
      u16* hp = H + (size_t)row * DIM + bn + wcol + l16;
#pragma unroll
      for (int j = 0; j < 4; j++) hp[j * 16] = f2bf(acc[i][j][r]);
    }
  }

  // ---- fused attention dots: partial over this block's 128 cols ----
  float as_j[4], ad_j[4];
#pragma unroll
  for (int j = 0; j < 4; j++) {
    int col = bn + wcol + j * 16 + l16;
    as_j[j] = atts[col];
    ad_j[j] = attd[col];
  }
#pragma unroll
  for (int i = 0; i < 4; i++) {
#pragma unroll
    for (int r = 0; r < 4; r++) {
      float ps = acc[i][0][r] * as_j[0] + acc[i][1][r] * as_j[1]
               + acc[i][2][r] * as_j[2] + acc[i][3][r] * as_j[3];
      float pd = acc[i][0][r] * ad_j[0] + acc[i][1][r] * ad_j[1]
               + acc[i][2][r] * ad_j[2] + acc[i][3][r] * ad_j[3];
#pragma unroll
      for (int d = 1; d < 16; d <<= 1) {
        ps += __shfl_xor(ps, d);
        pd += __shfl_xor(pd, d);
      }
      int row = bm + wrow + i * 16 + quad * 4 + r;
      if (l16 == 0 && row < N_NODES) {
        atomicAdd(&a_s[row], ps);
        atomicAdd(&a_d[row], pd);
      }
    }
  }
}

// -------------------- K4/K5/K6: counting sort by dst -----------------------
__global__ __launch_bounds__(256) void k_hist(const int* __restrict__ ei,
                                              int* __restrict__ counts) {
  int i = blockIdx.x * 256 + threadIdx.x;
  if (i >= ETOT) return;
  int d = (i < NEDGE) ? ei[NEDGE + i] : (i - NEDGE);
  atomicAdd(&counts[d], 1);
}

__global__ __launch_bounds__(1024) void k_scan(const int* __restrict__ counts,
                                               int* __restrict__ off,
                                               int* __restrict__ cursor) {
  __shared__ int wsum[16];
  __shared__ int s_total;
  int tid = threadIdx.x, lane = tid & 63, wid = tid >> 6;
  int carry = 0;
  for (int base = 0; base < N_NODES; base += 1024) {
    int i = base + tid;
    int v = (i < N_NODES) ? counts[i] : 0;
    int x = v;
#pragma unroll
    for (int d = 1; d < 64; d <<= 1) {
      int y = __shfl_up(x, d);
      if (lane >= d) x += y;
    }
    if (lane == 63) wsum[wid] = x;
    __syncthreads();
    if (tid == 0) {
      int run = 0;
#pragma unroll
      for (int w = 0; w < 16; w++) { int tv = wsum[w]; wsum[w] = run; run += tv; }
      s_total = run;
    }
    __syncthreads();
    int excl = x - v + wsum[wid] + carry;
    if (i < N_NODES) { off[i] = excl; cursor[i] = excl; }
    carry += s_total;
    __syncthreads();
  }
  if (tid == 0) off[N_NODES] = carry;
}

__global__ __launch_bounds__(256) void k_scatter(const int* __restrict__ ei,
                                                 int* __restrict__ cursor,
                                                 int* __restrict__ perm) {
  int i = blockIdx.x * 256 + threadIdx.x;
  if (i >= ETOT) return;
  int d = (i < NEDGE) ? ei[NEDGE + i] : (i - NEDGE);
  int slot = atomicAdd(&cursor[d], 1);
  perm[slot] = i;
}

// ----- K7: segment softmax + attention dropout + aggregation + stats -------
__global__ __launch_bounds__(256) void k_aggregate(
    const int* __restrict__ ei, const int* __restrict__ off, const int* __restrict__ perm,
    const float* __restrict__ a_s, const float* __restrict__ a_d,
    const u16* __restrict__ h, const float* __restrict__ bias,
    float* __restrict__ oa, float* __restrict__ colpart,
    float* __restrict__ ssqpart, u32 ka0, u32 ka1) {
  __shared__ float lbuf[4][512];
  int wid = threadIdx.x >> 6;
  int node = blockIdx.x * 4 + wid;
  int lane = threadIdx.x & 63;
  int beg = off[node], end = off[node + 1];
  int deg = end - beg;
  float adn = a_d[node];

  float acc[8] = {0.f, 0.f, 0.f, 0.f, 0.f, 0.f, 0.f, 0.f};

  if (deg <= 64) {
    int idx = beg + lane;
    bool valid = idx < end;
    int s = 0;
    float lg = -3.0e38f;
    u32 keepbits = 0;
    if (valid) {
      int eid = perm[idx];
      s = (eid < NEDGE) ? ei[eid] : (eid - NEDGE);
      lg = a_s[s] + adn;
      lg = (lg < 0.f) ? 0.2f * lg : lg;
      keepbits = tf_fold(ka0, ka1, (u32)eid);
    }
    float mx = lg;
#pragma unroll
    for (int d = 1; d < 64; d <<= 1) mx = fmaxf(mx, __shfl_xor(mx, d));
    float ee = valid ? expf(lg - mx) : 0.f;
    float ssum = ee;
#pragma unroll
    for (int d = 1; d < 64; d <<= 1) ssum += __shfl_xor(ssum, d);
    float inv_s = 2.5f / (ssum + 1e-16f);
    float w = (valid && ((keepbits >> 9) < 3355444u)) ? ee * inv_s : 0.f;

    for (int j = 0; j < deg; j++) {
      float wj = __shfl(w, j);
      if (wj != 0.f) {
        int sj = __shfl(s, j);
        uint4 hv = *(const uint4*)(h + (size_t)sj * DIM + lane * 8);
        u32 hw[4] = {hv.x, hv.y, hv.z, hv.w};
#pragma unroll
        for (int p = 0; p < 4; p++) {
          acc[2 * p]     += wj * bf2f(hw[p] & 0xffffu);
          acc[2 * p + 1] += wj * bf2f(hw[p] >> 16);
        }
      }
    }
  } else {
    float mx = -3.0e38f;
    for (int base = beg; base < end; base += 64) {
      int idx = base + lane;
      if (idx < end) {
        int eid = perm[idx];
        int s = (eid < NEDGE) ? ei[eid] : (eid - NEDGE);
        float lg = a_s[s] + adn;
        lg = (lg < 0.f) ? 0.2f * lg : lg;
        mx = fmaxf(mx, lg);
      }
    }
#pragma unroll
    for (int d = 1; d < 64; d <<= 1) mx = fmaxf(mx, __shfl_xor(mx, d));
    float ssum = 0.f;
    for (int base = beg; base < end; base += 64) {
      int idx = base + lane;
      if (idx < end) {
        int eid = perm[idx];
        int s = (eid < NEDGE) ? ei[eid] : (eid - NEDGE);
        float lg = a_s[s] + adn;
        lg = (lg < 0.f) ? 0.2f * lg : lg;
        ssum += expf(lg - mx);
      }
    }
#pragma unroll
    for (int d = 1; d < 64; d <<= 1) ssum += __shfl_xor(ssum, d);
    float inv_s = 2.5f / (ssum + 1e-16f);
    for (int base = beg; base < end; base += 64) {
      int idx = base + lane;
      float w = 0.f; int s = 0;
      if (idx < end) {
        int eid = perm[idx];
        s = (eid < NEDGE) ? ei[eid] : (eid - NEDGE);
        float lg = a_s[s] + adn;
        lg = (lg < 0.f) ? 0.2f * lg : lg;
        float ee = expf(lg - mx);
        u32 bits = tf_fold(ka0, ka1, (u32)eid);
        if ((bits >> 9) < 3355444u) w = ee * inv_s;
      }
      int cnt = min(64, end - base);
      for (int j = 0; j < cnt; j++) {
        float wj = __shfl(w, j);
        if (wj != 0.f) {
          int sj = __shfl(s, j);
          uint4 hv = *(const uint4*)(h + (size_t)sj * DIM + lane * 8);
          u32 hw[4] = {hv.x, hv.y, hv.z, hv.w};
#pragma unroll
          for (int p = 0; p < 4; p++) {
            acc[2 * p]     += wj * bf2f(hw[p] & 0xffffu);
            acc[2 * p + 1] += wj * bf2f(hw[p] >> 16);
          }
        }
      }
    }
  }

  float4 b0 = *(const float4*)(bias + lane * 8);
  float4 b1 = *(const float4*)(bias + lane * 8 + 4);
  float bb[8] = {b0.x, b0.y, b0.z, b0.w, b1.x, b1.y, b1.z, b1.w};
  float val[8];
#pragma unroll
  for (int t = 0; t < 8; t++) val[t] = acc[t] + bb[t];
  float* op = oa + (size_t)node * DIM + lane * 8;
#pragma unroll
  for (int t = 0; t < 8; t++) op[t] = val[t];
  *(float4*)&lbuf[wid][lane * 8]     = make_float4(val[0], val[1], val[2], val[3]);
  *(float4*)&lbuf[wid][lane * 8 + 4] = make_float4(val[4], val[5], val[6], val[7]);
  __syncthreads();

  int t = threadIdx.x;
  float s0 = 0.f, s1 = 0.f, ssl = 0.f;
#pragma unroll
  for (int w = 0; w < 4; w++) {
    float a = lbuf[w][t], b = lbuf[w][t + 256];
    s0 += a; s1 += b;
    ssl = fmaf(a, a, ssl);
    ssl = fmaf(b, b, ssl);
  }
  colpart[(size_t)blockIdx.x * 512 + t]       = s0;
  colpart[(size_t)blockIdx.x * 512 + 256 + t] = s1;
#pragma unroll
  for (int d = 1; d < 64; d <<= 1) ssl += __shfl_xor(ssl, d);
  __shared__ float wss[4];
  if ((t & 63) == 0) wss[t >> 6] = ssl;
  __syncthreads();
  if (t == 0) ssqpart[blockIdx.x] = wss[0] + wss[1] + wss[2] + wss[3];
}

// ------------- K8: reduce column partials + ssq (depth-60 atomics) ---------
__global__ __launch_bounds__(256) void k_redstats(const float* __restrict__ colpart,
                                                  const float* __restrict__ ssqpart,
                                                  float* __restrict__ colsum,
                                                  double* __restrict__ ssq) {
  int b = blockIdx.x;
  int t = threadIdx.x;
  int r0 = b * RED_ROWS;
  float s0 = 0.f, s1 = 0.f;
  for (int r = r0; r < r0 + RED_ROWS; r++) {
    s0 += colpart[(size_t)r * 512 + t];
    s1 += colpart[(size_t)r * 512 + 256 + t];
  }
  atomicAdd(&colsum[t], s0);
  atomicAdd(&colsum[t + 256], s1);
  float sl = (t < RED_ROWS) ? ssqpart[r0 + t] : 0.f;
#pragma unroll
  for (int d = 1; d < 64; d <<= 1) sl += __shfl_xor(sl, d);
  __shared__ float w4[4];
  if ((t & 63) == 0) w4[t >> 6] = sl;
  __syncthreads();
  if (t == 0) atomicAdd(ssq, (double)(w4[0] + w4[1] + w4[2] + w4[3]));
}

// --------------------------- K9: finalize scalars --------------------------
__global__ __launch_bounds__(512) void k_finalize(const float* __restrict__ colsum,
                                                  const double* __restrict__ ssq,
                                                  float* __restrict__ mu,
                                                  float* __restrict__ invp) {
  __shared__ double sred[8];
  int j = threadIdx.x;
  float m = colsum[j] * (1.0f / 30000.0f);
  mu[j] = m;
  double p = (double)m * (double)m;
#pragma unroll
  for (int d = 1; d < 64; d <<= 1) p += __shfl_xor(p, d);
  int lane = j & 63, wid = j >> 6;
  if (lane == 0) sred[wid] = p;
  __syncthreads();
  if (j == 0) {
    double smu2 = 0.0;
#pragma unroll
    for (int w = 0; w < 8; w++) smu2 += sred[w];
    double centered = ssq[0] - 30000.0 * smu2;
    double mean = centered * (1.0 / 30000.0);
    if (!(mean >= 0.0)) mean = 0.0;
    float rn = sqrtf(1e-6f + (float)mean);
    invp[0] = 1.0f / rn;
  }
}

// ----------------------- K10: center, scale, relu (fp32) -------------------
__global__ __launch_bounds__(256) void k_finalout(const float* __restrict__ oa,
                                                  const float* __restrict__ mu,
                                                  const float* __restrict__ invp,
                                                  float* __restrict__ out) {
  size_t gid = (size_t)blockIdx.x * 256 + threadIdx.x;
  size_t i0 = gid * 4;
  if (i0 >= (size_t)N_NODES * DIM) return;
  float inv = invp[0];
  int j = (int)(i0 & (DIM - 1));
  float4 v = *(const float4*)(oa + i0);
  float4 m = *(const float4*)(mu + j);
  float4 o;
  o.x = (v.x - m.x) * inv; o.x = (o.x < 0.f) ? 0.f : o.x;
  o.y = (v.y - m.y) * inv; o.y = (o.y < 0.f) ? 0.f : o.y;
  o.z = (v.z - m.z) * inv; o.z = (o.z < 0.f) ? 0.f : o.z;
  o.w = (v.w - m.w) * inv; o.w = (o.w < 0.f) ? 0.f : o.w;
  *(float4*)(out + i0) = o;
}

// ---------------------------------------------------------------------------
extern "C" void kernel_launch(void* const* d_in, const int* in_sizes, int n_in,
                              void* d_out, int out_size, void* d_ws, size_t ws_size,
                              hipStream_t stream) {
  const float* x    = (const float*)d_in[0];
  const int*   ei   = (const int*)d_in[1];
  const float* W    = (const float*)d_in[2];
  const float* atts = (const float*)d_in[3];
  const float* attd = (const float*)d_in[4];
  const float* bias = (const float*)d_in[5];
  float* out = (float*)d_out;
  char* ws = (char*)d_ws;

  float* oa     = (float*)(ws + 0);            // 61,440,000
  u16*   xd     = (u16*)(ws + 0);              // 30,801,920 (overlay, dead after GEMM)
  u16*   h      = (u16*)(ws + 61440000);       // 30,801,920
  u16*   Wt     = (u16*)(ws + 92241920);       //    524,288
  float* a_s    = (float*)(ws + 92766208);     //    120,064 (30000 used, zeroed)
  float* a_d    = (float*)(ws + 92886272);     //    120,064 (zeroed)
  int*   counts = (int*)(ws + 93006336);
  int*   offs   = (int*)(ws + 93126400);
  int*   cursor = (int*)(ws + 93246464);
  int*   perm   = (int*)(ws + 93366528);       //  1,320,000
  float* colsum = (float*)(ws + 94686528);
  float* mu     = (float*)(ws + 94688576);
  double* ssq   = (double*)(ws + 94690624);
  float* invp   = (float*)(ws + 94690688);     // end 94,690,752

  float* colpart = out;                        // d_out scratch until finalout
  float* ssqpart = out + (size_t)AGG_BLOCKS * 512;

  u32 kf0, kf1, ka0, ka1;
  threefry2x32(0u, 42u, 0u, 0u, kf0, kf1);
  threefry2x32(0u, 42u, 0u, 1u, ka0, ka1);

  hipMemsetAsync(counts, 0, 120064, stream);
  hipMemsetAsync((void*)colsum, 0, 4224, stream);
  hipMemsetAsync((void*)a_s, 0, 240128, stream);   // a_s + a_d (gemm atomics)

  k_cvtW<<<256, 256, 0, stream>>>(W, Wt);
  k_dropout<<<7520, 256, 0, stream>>>(x, xd, kf0, kf1);
  k_gemm<<<940, 256, 0, stream>>>(xd, Wt, h, atts, attd, a_s, a_d);
  k_hist<<<1290, 256, 0, stream>>>(ei, counts);
  k_scan<<<1, 1024, 0, stream>>>(counts, offs, cursor);
  k_scatter<<<1290, 256, 0, stream>>>(ei, cursor, perm);
  k_aggregate<<<AGG_BLOCKS, 256, 0, stream>>>(ei, offs, perm, a_s, a_d, h, bias,
                                              oa, colpart, ssqpart, ka0, ka1);
  k_redstats<<<RED_BLOCKS, 256, 0, stream>>>(colpart, ssqpart, colsum, ssq);
  k_finalize<<<1, 512, 0, stream>>>(colsum, ssq, mu, invp);
  k_finalout<<<15000, 256, 0, stream>>>(oa, mu, invp, out);
}

// Round 8
// 302.205 us; speedup vs baseline: 1.1740x; 1.1740x over previous
//
#include <hip/hip_runtime.h>
#include <stdint.h>
#include <math.h>

// ---------------------------------------------------------------------------
// GAT + PairNorm + ReLU, MI355X (gfx950).  Round 8.
// R7 post-mortem: BK=64 + fused-dot atomics blew WRITE_SIZE 30->183MB and
// k_gemm 46->96us (suspect: register pressure/scratch from 8 live uint4
// across barrier; atomics secondary). Also: SQ_LDS_BANK_CONFLICT was
// IDENTICAL (1,925,120) in R6/R7 -> conflicts are structural b128 volume,
// padding is not a lever. Changes:
//  * GEMM loop reverted to R6's proven BK=32 shape (VGPR 76, 45.9us).
//  * Fused dots kept but WITHOUT atomics: per-wave partial dots ->
//    aspart/adpart[8][30080] (in dead ws gap), folded by tiny k_dotsum.
//  * oa stored as bf16 (stats computed on quantized values): halves
//    aggregate write + finalout read.
// RNG: JAX partitionable threefry (fold-like split; bits = o0^o1).
// ---------------------------------------------------------------------------

#define N_NODES 30000
#define MPAD    30080
#define DIM     512
#define NEDGE   300000
#define ETOT    330000
#define AGG_BLOCKS 7500
#define RED_BLOCKS 60
#define RED_ROWS   125

typedef unsigned int u32;
typedef unsigned short u16;

typedef __attribute__((ext_vector_type(8))) short bf16x8;
typedef __attribute__((ext_vector_type(4))) float f32x4;

// ----------------------------- threefry2x32 --------------------------------
__host__ __device__ __forceinline__ void threefry2x32(u32 k0, u32 k1, u32 x0, u32 x1,
                                                      u32& o0, u32& o1) {
  u32 ks2 = k0 ^ k1 ^ 0x1BD11BDAu;
#define TF_R(r) { x0 += x1; x1 = (x1 << r) | (x1 >> (32 - r)); x1 ^= x0; }
  x0 += k0; x1 += k1;
  TF_R(13) TF_R(15) TF_R(26) TF_R(6)
  x0 += k1; x1 += ks2 + 1u;
  TF_R(17) TF_R(29) TF_R(16) TF_R(24)
  x0 += ks2; x1 += k0 + 2u;
  TF_R(13) TF_R(15) TF_R(26) TF_R(6)
  x0 += k0; x1 += k1 + 3u;
  TF_R(17) TF_R(29) TF_R(16) TF_R(24)
  x0 += k1; x1 += ks2 + 4u;
  TF_R(13) TF_R(15) TF_R(26) TF_R(6)
  x0 += ks2; x1 += k0 + 5u;
#undef TF_R
  o0 = x0; o1 = x1;
}

__device__ __forceinline__ u32 tf_fold(u32 k0, u32 k1, u32 idx) {
  u32 a, b;
  threefry2x32(k0, k1, 0u, idx, a, b);
  return a ^ b;
}

__device__ __forceinline__ float bf2f(u32 bits16) {
  return __uint_as_float(bits16 << 16);
}
__device__ __forceinline__ u16 f2bf(float f) {   // RNE
  u32 u = __float_as_uint(f);
  return (u16)((u + 0x7fffu + ((u >> 16) & 1u)) >> 16);
}

// ------------------- K0: W (fp32) -> Wt (bf16, transposed) -----------------
__global__ __launch_bounds__(256) void k_cvtW(const float* __restrict__ W,
                                              u16* __restrict__ Wt) {
  __shared__ u16 tile[32][33];
  int b = blockIdx.x;
  int bk = (b & 15) * 32, bn = (b >> 4) * 32;
  int c = threadIdx.x & 31, r = threadIdx.x >> 5;
#pragma unroll
  for (int rr = 0; rr < 32; rr += 8)
    tile[r + rr][c] = f2bf(W[(size_t)(bk + r + rr) * DIM + bn + c]);
  __syncthreads();
#pragma unroll
  for (int rr = 0; rr < 32; rr += 8)
    Wt[(size_t)(bn + r + rr) * DIM + bk + c] = tile[c][r + rr];
}

// ------------- K1: feature dropout (p=0.5) fp32 -> bf16, pad ---------------
__global__ __launch_bounds__(256) void k_dropout(const float* __restrict__ x,
                                                 u16* __restrict__ xd,
                                                 u32 kf0, u32 kf1) {
  size_t gid = (size_t)blockIdx.x * 256 + threadIdx.x;
  size_t i0 = gid * 8;
  if (i0 >= (size_t)MPAD * DIM) return;
  uint4 o = make_uint4(0u, 0u, 0u, 0u);
  if (i0 < (size_t)N_NODES * DIM) {
    float4 v0 = *(const float4*)(x + i0);
    float4 v1 = *(const float4*)(x + i0 + 4);
    float xv[8] = {v0.x, v0.y, v0.z, v0.w, v1.x, v1.y, v1.z, v1.w};
    u32 res[4];
#pragma unroll
    for (int p = 0; p < 4; p++) {
      u32 b0 = tf_fold(kf0, kf1, (u32)i0 + 2 * p);
      u32 b1 = tf_fold(kf0, kf1, (u32)i0 + 2 * p + 1);
      u32 r0 = (b0 >> 31) ? 0u : (u32)f2bf(2.0f * xv[2 * p]);     // keep <=> u<0.5
      u32 r1 = (b1 >> 31) ? 0u : (u32)f2bf(2.0f * xv[2 * p + 1]);
      res[p] = r0 | (r1 << 16);
    }
    o = make_uint4(res[0], res[1], res[2], res[3]);
  }
  *(uint4*)(xd + i0) = o;
}

// --------------------- K2: GEMM + fused attention dots ---------------------
// h[m][n] = sum_k xd[m][k]*Wt[n][k]. 128x128 tile, 4 waves, BK=32 (R6's
// proven loop). Epilogue: H (bf16) + per-wave partial dots -> aspart/adpart
// (NO atomics; slot = bn-block*2 + wcol-half).
__global__ __launch_bounds__(256) void k_gemm(const u16* __restrict__ A,
                                              const u16* __restrict__ B,
                                              u16* __restrict__ H,
                                              const float* __restrict__ atts,
                                              const float* __restrict__ attd,
                                              float* __restrict__ aspart,
                                              float* __restrict__ adpart) {
  __shared__ __align__(16) u16 lA[128 * 32];
  __shared__ __align__(16) u16 lB[128 * 32];
  const int bn = (blockIdx.x & 3) * 128;
  const int bm = (blockIdx.x >> 2) * 128;
  const int tid = threadIdx.x;
  const int wave = tid >> 6, lane = tid & 63;
  const int quad = lane >> 4, l16 = lane & 15;
  const int wrow = (wave & 1) * 64, wcol = (wave >> 1) * 64;

  f32x4 acc[4][4] = {};
  const int srow = tid >> 2;
  const int scq  = (tid & 3) * 8;

  for (int k0 = 0; k0 < DIM; k0 += 32) {
    uint4 va0 = *(const uint4*)(A + (size_t)(bm + srow) * DIM + k0 + scq);
    uint4 va1 = *(const uint4*)(A + (size_t)(bm + 64 + srow) * DIM + k0 + scq);
    uint4 vb0 = *(const uint4*)(B + (size_t)(bn + srow) * DIM + k0 + scq);
    uint4 vb1 = *(const uint4*)(B + (size_t)(bn + 64 + srow) * DIM + k0 + scq);
    __syncthreads();
    *(uint4*)(lA + srow * 32 + scq) = va0;
    *(uint4*)(lA + (64 + srow) * 32 + scq) = va1;
    *(uint4*)(lB + srow * 32 + scq) = vb0;
    *(uint4*)(lB + (64 + srow) * 32 + scq) = vb1;
    __syncthreads();

    bf16x8 af[4], bfr[4];
#pragma unroll
    for (int i = 0; i < 4; i++)
      af[i] = *(const bf16x8*)(lA + (wrow + i * 16 + l16) * 32 + quad * 8);
#pragma unroll
    for (int j = 0; j < 4; j++)
      bfr[j] = *(const bf16x8*)(lB + (wcol + j * 16 + l16) * 32 + quad * 8);
#pragma unroll
    for (int i = 0; i < 4; i++)
#pragma unroll
      for (int j = 0; j < 4; j++)
        acc[i][j] = __builtin_amdgcn_mfma_f32_16x16x32_bf16(af[i], bfr[j], acc[i][j], 0, 0, 0);
  }

  // ---- epilogue: H write (C/D: col=lane&15, row=quad*4+reg) ----
#pragma unroll
  for (int i = 0; i < 4; i++) {
#pragma unroll
    for (int r = 0; r < 4; r++) {
      int row = bm + wrow + i * 16 + quad * 4 + r;
      u16* hp = H + (size_t)row * DIM + bn + wcol + l16;
#pragma unroll
      for (int j = 0; j < 4; j++) hp[j * 16] = f2bf(acc[i][j][r]);
    }
  }

  // ---- fused attention dots: partial over this wave's 64 cols ----
  float as_j[4], ad_j[4];
#pragma unroll
  for (int j = 0; j < 4; j++) {
    int col = bn + wcol + j * 16 + l16;
    as_j[j] = atts[col];
    ad_j[j] = attd[col];
  }
  int slot = ((bn >> 7) << 1) + (wcol >> 6);   // 0..7
#pragma unroll
  for (int i = 0; i < 4; i++) {
#pragma unroll
    for (int r = 0; r < 4; r++) {
      float ps = acc[i][0][r] * as_j[0] + acc[i][1][r] * as_j[1]
               + acc[i][2][r] * as_j[2] + acc[i][3][r] * as_j[3];
      float pd = acc[i][0][r] * ad_j[0] + acc[i][1][r] * ad_j[1]
               + acc[i][2][r] * ad_j[2] + acc[i][3][r] * ad_j[3];
#pragma unroll
      for (int d = 1; d < 16; d <<= 1) {
        ps += __shfl_xor(ps, d);
        pd += __shfl_xor(pd, d);
      }
      int row = bm + wrow + i * 16 + quad * 4 + r;
      if (l16 == 0) {
        aspart[slot * MPAD + row] = ps;
        adpart[slot * MPAD + row] = pd;
      }
    }
  }
}

// -------------- K3: fold 8 partial dot slots -> a_s, a_d -------------------
__global__ __launch_bounds__(256) void k_dotsum(const float* __restrict__ aspart,
                                                const float* __restrict__ adpart,
                                                float* __restrict__ a_s,
                                                float* __restrict__ a_d) {
  int i = blockIdx.x * 256 + threadIdx.x;
  if (i >= N_NODES) return;
  float s = 0.f, d = 0.f;
#pragma unroll
  for (int k = 0; k < 8; k++) {
    s += aspart[k * MPAD + i];
    d += adpart[k * MPAD + i];
  }
  a_s[i] = s;
  a_d[i] = d;
}

// -------------------- K4/K5/K6: counting sort by dst -----------------------
__global__ __launch_bounds__(256) void k_hist(const int* __restrict__ ei,
                                              int* __restrict__ counts) {
  int i = blockIdx.x * 256 + threadIdx.x;
  if (i >= ETOT) return;
  int d = (i < NEDGE) ? ei[NEDGE + i] : (i - NEDGE);
  atomicAdd(&counts[d], 1);
}

__global__ __launch_bounds__(1024) void k_scan(const int* __restrict__ counts,
                                               int* __restrict__ off,
                                               int* __restrict__ cursor) {
  __shared__ int wsum[16];
  __shared__ int s_total;
  int tid = threadIdx.x, lane = tid & 63, wid = tid >> 6;
  int carry = 0;
  for (int base = 0; base < N_NODES; base += 1024) {
    int i = base + tid;
    int v = (i < N_NODES) ? counts[i] : 0;
    int x = v;
#pragma unroll
    for (int d = 1; d < 64; d <<= 1) {
      int y = __shfl_up(x, d);
      if (lane >= d) x += y;
    }
    if (lane == 63) wsum[wid] = x;
    __syncthreads();
    if (tid == 0) {
      int run = 0;
#pragma unroll
      for (int w = 0; w < 16; w++) { int tv = wsum[w]; wsum[w] = run; run += tv; }
      s_total = run;
    }
    __syncthreads();
    int excl = x - v + wsum[wid] + carry;
    if (i < N_NODES) { off[i] = excl; cursor[i] = excl; }
    carry += s_total;
    __syncthreads();
  }
  if (tid == 0) off[N_NODES] = carry;
}

__global__ __launch_bounds__(256) void k_scatter(const int* __restrict__ ei,
                                                 int* __restrict__ cursor,
                                                 int* __restrict__ perm) {
  int i = blockIdx.x * 256 + threadIdx.x;
  if (i >= ETOT) return;
  int d = (i < NEDGE) ? ei[NEDGE + i] : (i - NEDGE);
  int slot = atomicAdd(&cursor[d], 1);
  perm[slot] = i;
}

// ----- K7: segment softmax + attention dropout + aggregation + stats -------
// oa stored bf16; column/ssq stats computed on the quantized values.
__global__ __launch_bounds__(256) void k_aggregate(
    const int* __restrict__ ei, const int* __restrict__ off, const int* __restrict__ perm,
    const float* __restrict__ a_s, const float* __restrict__ a_d,
    const u16* __restrict__ h, const float* __restrict__ bias,
    u16* __restrict__ oa, float* __restrict__ colpart,
    float* __restrict__ ssqpart, u32 ka0, u32 ka1) {
  __shared__ float lbuf[4][512];
  int wid = threadIdx.x >> 6;
  int node = blockIdx.x * 4 + wid;
  int lane = threadIdx.x & 63;
  int beg = off[node], end = off[node + 1];
  int deg = end - beg;
  float adn = a_d[node];

  float acc[8] = {0.f, 0.f, 0.f, 0.f, 0.f, 0.f, 0.f, 0.f};

  if (deg <= 64) {
    int idx = beg + lane;
    bool valid = idx < end;
    int s = 0;
    float lg = -3.0e38f;
    u32 keepbits = 0;
    if (valid) {
      int eid = perm[idx];
      s = (eid < NEDGE) ? ei[eid] : (eid - NEDGE);
      lg = a_s[s] + adn;
      lg = (lg < 0.f) ? 0.2f * lg : lg;
      keepbits = tf_fold(ka0, ka1, (u32)eid);
    }
    float mx = lg;
#pragma unroll
    for (int d = 1; d < 64; d <<= 1) mx = fmaxf(mx, __shfl_xor(mx, d));
    float ee = valid ? expf(lg - mx) : 0.f;
    float ssum = ee;
#pragma unroll
    for (int d = 1; d < 64; d <<= 1) ssum += __shfl_xor(ssum, d);
    float inv_s = 2.5f / (ssum + 1e-16f);
    float w = (valid && ((keepbits >> 9) < 3355444u)) ? ee * inv_s : 0.f;

    for (int j = 0; j < deg; j++) {
      float wj = __shfl(w, j);
      if (wj != 0.f) {
        int sj = __shfl(s, j);
        uint4 hv = *(const uint4*)(h + (size_t)sj * DIM + lane * 8);
        u32 hw[4] = {hv.x, hv.y, hv.z, hv.w};
#pragma unroll
        for (int p = 0; p < 4; p++) {
          acc[2 * p]     += wj * bf2f(hw[p] & 0xffffu);
          acc[2 * p + 1] += wj * bf2f(hw[p] >> 16);
        }
      }
    }
  } else {
    float mx = -3.0e38f;
    for (int base = beg; base < end; base += 64) {
      int idx = base + lane;
      if (idx < end) {
        int eid = perm[idx];
        int s = (eid < NEDGE) ? ei[eid] : (eid - NEDGE);
        float lg = a_s[s] + adn;
        lg = (lg < 0.f) ? 0.2f * lg : lg;
        mx = fmaxf(mx, lg);
      }
    }
#pragma unroll
    for (int d = 1; d < 64; d <<= 1) mx = fmaxf(mx, __shfl_xor(mx, d));
    float ssum = 0.f;
    for (int base = beg; base < end; base += 64) {
      int idx = base + lane;
      if (idx < end) {
        int eid = perm[idx];
        int s = (eid < NEDGE) ? ei[eid] : (eid - NEDGE);
        float lg = a_s[s] + adn;
        lg = (lg < 0.f) ? 0.2f * lg : lg;
        ssum += expf(lg - mx);
      }
    }
#pragma unroll
    for (int d = 1; d < 64; d <<= 1) ssum += __shfl_xor(ssum, d);
    float inv_s = 2.5f / (ssum + 1e-16f);
    for (int base = beg; base < end; base += 64) {
      int idx = base + lane;
      float w = 0.f; int s = 0;
      if (idx < end) {
        int eid = perm[idx];
        s = (eid < NEDGE) ? ei[eid] : (eid - NEDGE);
        float lg = a_s[s] + adn;
        lg = (lg < 0.f) ? 0.2f * lg : lg;
        float ee = expf(lg - mx);
        u32 bits = tf_fold(ka0, ka1, (u32)eid);
        if ((bits >> 9) < 3355444u) w = ee * inv_s;
      }
      int cnt = min(64, end - base);
      for (int j = 0; j < cnt; j++) {
        float wj = __shfl(w, j);
        if (wj != 0.f) {
          int sj = __shfl(s, j);
          uint4 hv = *(const uint4*)(h + (size_t)sj * DIM + lane * 8);
          u32 hw[4] = {hv.x, hv.y, hv.z, hv.w};
#pragma unroll
          for (int p = 0; p < 4; p++) {
            acc[2 * p]     += wj * bf2f(hw[p] & 0xffffu);
            acc[2 * p + 1] += wj * bf2f(hw[p] >> 16);
          }
        }
      }
    }
  }

  // epilogue: add bias, quantize to bf16, store oa, stats on quantized vals
  float4 b0 = *(const float4*)(bias + lane * 8);
  float4 b1 = *(const float4*)(bias + lane * 8 + 4);
  float bb[8] = {b0.x, b0.y, b0.z, b0.w, b1.x, b1.y, b1.z, b1.w};
  u32 res[4];
  float vq[8];
#pragma unroll
  for (int p = 0; p < 4; p++) {
    u16 q0 = f2bf(acc[2 * p]     + bb[2 * p]);
    u16 q1 = f2bf(acc[2 * p + 1] + bb[2 * p + 1]);
    res[p] = (u32)q0 | ((u32)q1 << 16);
    vq[2 * p]     = bf2f(q0);
    vq[2 * p + 1] = bf2f(q1);
  }
  *(uint4*)(oa + (size_t)node * DIM + lane * 8) = make_uint4(res[0], res[1], res[2], res[3]);
  *(float4*)&lbuf[wid][lane * 8]     = make_float4(vq[0], vq[1], vq[2], vq[3]);
  *(float4*)&lbuf[wid][lane * 8 + 4] = make_float4(vq[4], vq[5], vq[6], vq[7]);
  __syncthreads();

  int t = threadIdx.x;
  float s0 = 0.f, s1 = 0.f, ssl = 0.f;
#pragma unroll
  for (int w = 0; w < 4; w++) {
    float a = lbuf[w][t], b = lbuf[w][t + 256];
    s0 += a; s1 += b;
    ssl = fmaf(a, a, ssl);
    ssl = fmaf(b, b, ssl);
  }
  colpart[(size_t)blockIdx.x * 512 + t]       = s0;
  colpart[(size_t)blockIdx.x * 512 + 256 + t] = s1;
#pragma unroll
  for (int d = 1; d < 64; d <<= 1) ssl += __shfl_xor(ssl, d);
  __shared__ float wss[4];
  if ((t & 63) == 0) wss[t >> 6] = ssl;
  __syncthreads();
  if (t == 0) ssqpart[blockIdx.x] = wss[0] + wss[1] + wss[2] + wss[3];
}

// ------------- K8: reduce column partials + ssq (depth-60 atomics) ---------
__global__ __launch_bounds__(256) void k_redstats(const float* __restrict__ colpart,
                                                  const float* __restrict__ ssqpart,
                                                  float* __restrict__ colsum,
                                                  double* __restrict__ ssq) {
  int b = blockIdx.x;
  int t = threadIdx.x;
  int r0 = b * RED_ROWS;
  float s0 = 0.f, s1 = 0.f;
  for (int r = r0; r < r0 + RED_ROWS; r++) {
    s0 += colpart[(size_t)r * 512 + t];
    s1 += colpart[(size_t)r * 512 + 256 + t];
  }
  atomicAdd(&colsum[t], s0);
  atomicAdd(&colsum[t + 256], s1);
  float sl = (t < RED_ROWS) ? ssqpart[r0 + t] : 0.f;
#pragma unroll
  for (int d = 1; d < 64; d <<= 1) sl += __shfl_xor(sl, d);
  __shared__ float w4[4];
  if ((t & 63) == 0) w4[t >> 6] = sl;
  __syncthreads();
  if (t == 0) atomicAdd(ssq, (double)(w4[0] + w4[1] + w4[2] + w4[3]));
}

// --------------------------- K9: finalize scalars --------------------------
__global__ __launch_bounds__(512) void k_finalize(const float* __restrict__ colsum,
                                                  const double* __restrict__ ssq,
                                                  float* __restrict__ mu,
                                                  float* __restrict__ invp) {
  __shared__ double sred[8];
  int j = threadIdx.x;
  float m = colsum[j] * (1.0f / 30000.0f);
  mu[j] = m;
  double p = (double)m * (double)m;
#pragma unroll
  for (int d = 1; d < 64; d <<= 1) p += __shfl_xor(p, d);
  int lane = j & 63, wid = j >> 6;
  if (lane == 0) sred[wid] = p;
  __syncthreads();
  if (j == 0) {
    double smu2 = 0.0;
#pragma unroll
    for (int w = 0; w < 8; w++) smu2 += sred[w];
    double centered = ssq[0] - 30000.0 * smu2;
    double mean = centered * (1.0 / 30000.0);
    if (!(mean >= 0.0)) mean = 0.0;
    float rn = sqrtf(1e-6f + (float)mean);
    invp[0] = 1.0f / rn;
  }
}

// ---------------- K10: center, scale, relu (bf16 oa -> fp32 out) -----------
__global__ __launch_bounds__(256) void k_finalout(const u16* __restrict__ oa,
                                                  const float* __restrict__ mu,
                                                  const float* __restrict__ invp,
                                                  float* __restrict__ out) {
  size_t gid = (size_t)blockIdx.x * 256 + threadIdx.x;
  size_t i0 = gid * 8;
  if (i0 >= (size_t)N_NODES * DIM) return;
  float inv = invp[0];
  int j = (int)(i0 & (DIM - 1));
  uint4 v = *(const uint4*)(oa + i0);
  u32 w[4] = {v.x, v.y, v.z, v.w};
  float o[8];
#pragma unroll
  for (int p = 0; p < 4; p++) {
    float z0 = (bf2f(w[p] & 0xffffu) - mu[j + 2 * p]) * inv;
    float z1 = (bf2f(w[p] >> 16)     - mu[j + 2 * p + 1]) * inv;
    o[2 * p]     = (z0 < 0.f) ? 0.f : z0;
    o[2 * p + 1] = (z1 < 0.f) ? 0.f : z1;
  }
  *(float4*)(out + i0)     = make_float4(o[0], o[1], o[2], o[3]);
  *(float4*)(out + i0 + 4) = make_float4(o[4], o[5], o[6], o[7]);
}

// ---------------------------------------------------------------------------
extern "C" void kernel_launch(void* const* d_in, const int* in_sizes, int n_in,
                              void* d_out, int out_size, void* d_ws, size_t ws_size,
                              hipStream_t stream) {
  const float* x    = (const float*)d_in[0];
  const int*   ei   = (const int*)d_in[1];
  const float* W    = (const float*)d_in[2];
  const float* atts = (const float*)d_in[3];
  const float* attd = (const float*)d_in[4];
  const float* bias = (const float*)d_in[5];
  float* out = (float*)d_out;
  char* ws = (char*)d_ws;

  // oa is now bf16 and overlays xd at ws+0 (xd dead after gemm, oa written
  // by aggregate). aspart/adpart live in the dead gap [32M, 61.4M) between
  // gemm (writes them) and aggregate; k_dotsum consumes them first.
  u16*   xd      = (u16*)(ws + 0);             // 30,801,920
  u16*   oa      = (u16*)(ws + 0);             // 30,720,000 (overlay)
  float* aspart  = (float*)(ws + 32000000);    // 8*30080*4 = 962,560
  float* adpart  = (float*)(ws + 33000000);    //   962,560
  u16*   h       = (u16*)(ws + 61440000);      // 30,801,920
  u16*   Wt      = (u16*)(ws + 92241920);      //    524,288
  float* a_s     = (float*)(ws + 92766208);    //    120,064
  float* a_d     = (float*)(ws + 92886272);    //    120,064
  int*   counts  = (int*)(ws + 93006336);
  int*   offs    = (int*)(ws + 93126400);
  int*   cursor  = (int*)(ws + 93246464);
  int*   perm    = (int*)(ws + 93366528);      //  1,320,000
  float* colsum  = (float*)(ws + 94686528);
  float* mu      = (float*)(ws + 94688576);
  double* ssq    = (double*)(ws + 94690624);
  float* invp    = (float*)(ws + 94690688);    // end 94,690,752

  float* colpart = out;                        // d_out scratch until finalout
  float* ssqpart = out + (size_t)AGG_BLOCKS * 512;

  u32 kf0, kf1, ka0, ka1;
  threefry2x32(0u, 42u, 0u, 0u, kf0, kf1);
  threefry2x32(0u, 42u, 0u, 1u, ka0, ka1);

  hipMemsetAsync(counts, 0, 120064, stream);
  hipMemsetAsync((void*)colsum, 0, 4224, stream);

  k_cvtW<<<256, 256, 0, stream>>>(W, Wt);
  k_dropout<<<7520, 256, 0, stream>>>(x, xd, kf0, kf1);
  k_gemm<<<940, 256, 0, stream>>>(xd, Wt, h, atts, attd, aspart, adpart);
  k_dotsum<<<118, 256, 0, stream>>>(aspart, adpart, a_s, a_d);
  k_hist<<<1290, 256, 0, stream>>>(ei, counts);
  k_scan<<<1, 1024, 0, stream>>>(counts, offs, cursor);
  k_scatter<<<1290, 256, 0, stream>>>(ei, cursor, perm);
  k_aggregate<<<AGG_BLOCKS, 256, 0, stream>>>(ei, offs, perm, a_s, a_d, h, bias,
                                              oa, colpart, ssqpart, ka0, ka1);
  k_redstats<<<RED_BLOCKS, 256, 0, stream>>>(colpart, ssqpart, colsum, ssq);
  k_finalize<<<1, 512, 0, stream>>>(colsum, ssq, mu, invp);
  k_finalout<<<7500, 256, 0, stream>>>(oa, mu, invp, out);
}